// Round 9
// baseline (249.770 us; speedup 1.0000x reference)
//
#include <hip/hip_runtime.h>
#include <hip/hip_bf16.h>

// R9: both passes use the contiguous 8-lane/point pattern (1KB per wave-instr,
// the 6.29 TB/s copy-bench pattern); all subgroup reductions via DPP (zero DS
// ops); k_final fused into k_pool via last-block-done + agent-scope loads
// (R5-proven). z/len cancel under L2-normalize; no softmax max-shift
// (shift-invariant, small scores; absmax 6e-5 across R1-R8).
//
//  k_stats: 8 lanes/point, dot via 3 DPP adds; f64 sum(s),sum(s^2) with 8x
//           lane redundancy (divided out as 1/(8N)); per-block plain stores.
//           Block 0 zeroes pooled + done counter (k_pool-only data; safe).
//  k_pool : per-wave reduce of the 2048 stat partials (L3-hot, deterministic)
//           -> c1,c2. Hot loop: e = exp((c1*s+c2)*rm); acc += x*e; DPP sums.
//           Segment-uniform fast path; slow path for ~31 boundary waves.
//           Last block (device atomic counter) L2-normalizes pooled -> out.

#define TPB 256
#define NBLK 2048

template <int CTRL>
__device__ __forceinline__ float dpp_add(float v) {
  int sh = __builtin_amdgcn_update_dpp(
      0, __builtin_bit_cast(int, v), CTRL, 0xF, 0xF, true);
  return v + __builtin_bit_cast(float, sh);
}
// xor1 = quad_perm[1,0,3,2] = 0xB1 ; xor2 = quad_perm[2,3,0,1] = 0x4E ;
// lane^7 (completes the 8-lane sum) = ROW_HALF_MIRROR = 0x141

__device__ __forceinline__ float sub8_sum(float v) {
  v = dpp_add<0xB1>(v);
  v = dpp_add<0x4E>(v);
  v = dpp_add<0x141>(v);
  return v;
}

__global__ __launch_bounds__(TPB) void k_stats(
    const float* __restrict__ x, const float* __restrict__ w,
    const float* __restrict__ bptr, double* __restrict__ sumsp,
    float* __restrict__ pooled, int* __restrict__ done, int N, int chunk) {
  if (blockIdx.x == 0) {            // pooled/done used only by k_pool (launched after)
    for (int i = threadIdx.x; i < 1024; i += TPB) pooled[i] = 0.f;
    if (threadIdx.x == 0) *done = 0;
  }
  const int tid  = threadIdx.x;
  const int lane = tid & 63;
  const int sub  = lane >> 3;      // point slot within the wave's 8-point batch
  const int cg   = lane & 7;       // which float4 of the point
  const float4 w4 = reinterpret_cast<const float4*>(w)[cg];
  const float bv = bptr[0];

  int gid = blockIdx.x * (TPB >> 6) + (tid >> 6);
  int p0 = gid * chunk;            // chunk % 8 == 0
  double accS = 0.0, accS2 = 0.0;
  if (p0 < N) {
    int p1 = p0 + chunk; if (p1 > N) p1 = N;
    const float4* x4 = reinterpret_cast<const float4*>(x);
    int nfull = (p1 - p0) & ~7;
    int pb = p0;
#pragma unroll 8
    for (; pb < p0 + nfull; pb += 8) {
      int p = pb + sub;
      float4 xv = x4[(size_t)p * 8 + cg];    // wave covers 1KB contiguous
      float d = fmaf(xv.x, w4.x, fmaf(xv.y, w4.y, fmaf(xv.z, w4.z, xv.w * w4.w)));
      d = sub8_sum(d);                       // all 8 lanes now hold the full dot
      float s = d + bv;
      accS  += (double)s;                    // 8x redundancy, divided out below
      accS2 += (double)s * (double)s;
    }
    if (pb < p1) {                           // unreachable for N%8==0; kept safe
      int p = pb + sub;
      bool valid = (p < p1);
      int pc = valid ? p : p1 - 1;
      float4 xv = x4[(size_t)pc * 8 + cg];
      float d = fmaf(xv.x, w4.x, fmaf(xv.y, w4.y, fmaf(xv.z, w4.z, xv.w * w4.w)));
      d = sub8_sum(d);
      float s = d + bv;
      if (valid) { accS += (double)s; accS2 += (double)s * (double)s; }
    }
  }
#pragma unroll
  for (int off = 32; off > 0; off >>= 1) {
    accS  += __shfl_down(accS, off, 64);
    accS2 += __shfl_down(accS2, off, 64);
  }
  __shared__ double lds[8];
  int wid = tid >> 6;
  if (lane == 0) { lds[wid*2] = accS; lds[wid*2+1] = accS2; }
  __syncthreads();
  if (tid == 0) {
    sumsp[blockIdx.x * 2]     = lds[0] + lds[2] + lds[4] + lds[6];
    sumsp[blockIdx.x * 2 + 1] = lds[1] + lds[3] + lds[5] + lds[7];
  }
}

__global__ __launch_bounds__(TPB) void k_pool(
    const float* __restrict__ x, const int* __restrict__ seg,
    const float* __restrict__ w, const float* __restrict__ bptr,
    const double* __restrict__ sumsp, const float* __restrict__ gptr,
    const float* __restrict__ betap, float* __restrict__ pooled,
    int* __restrict__ done, float* __restrict__ out, int N, int chunk) {
  const int tid = threadIdx.x;
  // per-wave reduce of the 2048 stat partials (32KB, L3-hot, deterministic ->
  // identical mu/var in every wave); broadcast from lane 0.
  double a = 0.0, c = 0.0;
  for (int k = tid & 63; k < NBLK; k += 64) {
    a += sumsp[k * 2];
    c += sumsp[k * 2 + 1];
  }
#pragma unroll
  for (int off = 32; off > 0; off >>= 1) {
    a += __shfl_down(a, off, 64);
    c += __shfl_down(c, off, 64);
  }
  a = __shfl(a, 0, 64);
  c = __shfl(c, 0, 64);
  const double invCnt = 1.0 / (8.0 * (double)N);   // 8x lane redundancy
  const double mu  = a * invCnt;
  const double var = c * invCnt - mu * mu;
  const float inv = (float)(1.0 / sqrt(var + 1e-5));
  const float c1 = gptr[0] * inv;                  // s_bn = c1*s + c2
  const float c2 = betap[0] - c1 * (float)mu;

  const int lane = tid & 63;
  const int sub  = lane >> 3;
  const int cg   = lane & 7;
  const float4 w4 = reinterpret_cast<const float4*>(w)[cg];
  const float bv = bptr[0];

  int gid = blockIdx.x * (TPB >> 6) + (tid >> 6);
  int p0 = gid * chunk;                     // chunk % 8 == 0
  if (p0 < N) {
    int p1 = p0 + chunk; if (p1 > N) p1 = N;
    const float4* x4 = reinterpret_cast<const float4*>(x);
    float4 acc = make_float4(0.f, 0.f, 0.f, 0.f);
    const int segA = seg[p0];
    const int segB = seg[p1 - 1];

    if (segA == segB) {
      // ---- fast path: whole chunk in one segment; DPP-only reductions ----
      int nfull = (p1 - p0) & ~7;
      int pb = p0;
#pragma unroll 8
      for (; pb < p0 + nfull; pb += 8) {
        int p = pb + sub;
        float4 xv = x4[(size_t)p * 8 + cg];
        float d = fmaf(xv.x, w4.x, fmaf(xv.y, w4.y, fmaf(xv.z, w4.z, xv.w * w4.w)));
        float r = (xv.x + xv.y) + (xv.z + xv.w);
        d = sub8_sum(d);
        r = sub8_sum(r);
        float e = __expf(fmaf(c1, d + bv, c2) * (r * 0.03125f));
        acc.x = fmaf(xv.x, e, acc.x);
        acc.y = fmaf(xv.y, e, acc.y);
        acc.z = fmaf(xv.z, e, acc.z);
        acc.w = fmaf(xv.w, e, acc.w);
      }
      if (pb < p1) {                 // unreachable for N%8==0; kept safe
        int p = pb + sub;
        bool valid = (p < p1);
        int pc = valid ? p : p1 - 1;
        float4 xv = x4[(size_t)pc * 8 + cg];
        float d = fmaf(xv.x, w4.x, fmaf(xv.y, w4.y, fmaf(xv.z, w4.z, xv.w * w4.w)));
        float r = (xv.x + xv.y) + (xv.z + xv.w);
        d = sub8_sum(d);
        r = sub8_sum(r);
        float e = valid ? __expf(fmaf(c1, d + bv, c2) * (r * 0.03125f)) : 0.f;
        acc.x = fmaf(xv.x, e, acc.x);
        acc.y = fmaf(xv.y, e, acc.y);
        acc.z = fmaf(xv.z, e, acc.z);
        acc.w = fmaf(xv.w, e, acc.w);
      }
#pragma unroll
      for (int off = 8; off < 64; off <<= 1) {   // reduce across the 8 point slots
        acc.x += __shfl_xor(acc.x, off);
        acc.y += __shfl_xor(acc.y, off);
        acc.z += __shfl_xor(acc.z, off);
        acc.w += __shfl_xor(acc.w, off);
      }
      if (sub == 0) {
        atomicAdd(&pooled[segA * 32 + cg * 4 + 0], acc.x);
        atomicAdd(&pooled[segA * 32 + cg * 4 + 1], acc.y);
        atomicAdd(&pooled[segA * 32 + cg * 4 + 2], acc.z);
        atomicAdd(&pooled[segA * 32 + cg * 4 + 3], acc.w);
      }
    } else {
      // ---- slow path: chunk crosses a segment boundary (~31 waves total) ----
      int curSeg = segA;
      for (int pb = p0; pb < p1; pb += 8) {
        int p = pb + sub;
        bool valid = (p < p1);
        int pc = valid ? p : p1 - 1;
        int sg = seg[pc];
        float4 xv = x4[(size_t)pc * 8 + cg];
        float d = fmaf(xv.x, w4.x, fmaf(xv.y, w4.y, fmaf(xv.z, w4.z, xv.w * w4.w)));
        float r = (xv.x + xv.y) + (xv.z + xv.w);
        d = sub8_sum(d);
        r = sub8_sum(r);
        float e = valid ? __expf(fmaf(c1, d + bv, c2) * (r * 0.03125f)) : 0.f;
        if (sg != curSeg) {
          atomicAdd(&pooled[curSeg * 32 + cg * 4 + 0], acc.x);
          atomicAdd(&pooled[curSeg * 32 + cg * 4 + 1], acc.y);
          atomicAdd(&pooled[curSeg * 32 + cg * 4 + 2], acc.z);
          atomicAdd(&pooled[curSeg * 32 + cg * 4 + 3], acc.w);
          acc = make_float4(0.f, 0.f, 0.f, 0.f);
          curSeg = sg;
        }
        acc.x = fmaf(xv.x, e, acc.x);
        acc.y = fmaf(xv.y, e, acc.y);
        acc.z = fmaf(xv.z, e, acc.z);
        acc.w = fmaf(xv.w, e, acc.w);
      }
      atomicAdd(&pooled[curSeg * 32 + cg * 4 + 0], acc.x);
      atomicAdd(&pooled[curSeg * 32 + cg * 4 + 1], acc.y);
      atomicAdd(&pooled[curSeg * 32 + cg * 4 + 2], acc.z);
      atomicAdd(&pooled[curSeg * 32 + cg * 4 + 3], acc.w);
    }
  }

  // ---- last-block-done: fused finalize (saves the k_final dispatch) ----
  __syncthreads();                         // all waves of this block flushed
  __shared__ int lastFlag;
  if (tid == 0) {
    __threadfence();                       // release my atomics
    int old = atomicAdd(done, 1);          // device-scope
    lastFlag = (old == NBLK - 1);
  }
  __syncthreads();
  if (lastFlag) {
    for (int i = tid; i < 1024; i += TPB) {
      // agent-scope loads: pooled was written by atomics from other XCDs
      float v = __hip_atomic_load(&pooled[i], __ATOMIC_RELAXED,
                                  __HIP_MEMORY_SCOPE_AGENT);
      float sq = v * v;
#pragma unroll
      for (int off = 16; off > 0; off >>= 1) sq += __shfl_xor(sq, off, 32);
      float norm = sqrtf(sq);               // 32 consecutive threads = one segment
      out[i] = v / fmaxf(norm, 1e-30f);     // z & len cancel under normalize
    }
  }
}

extern "C" void kernel_launch(void* const* d_in, const int* in_sizes, int n_in,
                              void* d_out, int out_size, void* d_ws, size_t ws_size,
                              hipStream_t stream) {
  const float* x     = (const float*)d_in[0];
  const float* w     = (const float*)d_in[1];
  const float* b     = (const float*)d_in[2];
  const float* gamma = (const float*)d_in[3];
  const float* beta  = (const float*)d_in[4];
  const int* seg     = (const int*)d_in[6];
  int N = in_sizes[6];          // 3,170,000
  float* out = (float*)d_out;

  char* ws = (char*)d_ws;
  double* sumsp  = (double*)ws;                        // NBLK*2 doubles (32 KB)
  float*  pooled = (float*)(ws + (size_t)NBLK * 16);   // 1024 floats
  int*    done   = (int*)(ws + (size_t)NBLK * 16 + 4096);

  const int nWaves = NBLK * (TPB / 64);      // 8192
  int chunk = (N + nWaves - 1) / nWaves;
  chunk = (chunk + 7) & ~7;                  // multiple of 8

  k_stats<<<NBLK, TPB, 0, stream>>>(x, w, b, sumsp, pooled, done, N, chunk);
  k_pool <<<NBLK, TPB, 0, stream>>>(x, seg, w, b, sumsp, gamma, beta, pooled,
                                    done, out, N, chunk);
}

// Round 10
// 175.257 us; speedup vs baseline: 1.4252x; 1.4252x over previous
//
#include <hip/hip_runtime.h>
#include <hip/hip_bf16.h>

// R10 = R8 (173us, best) + ONE change: k_final fused into k_pool via a
// FENCELESS last-block-done (no __threadfence: pooled atomicAdds are
// device-scope and __syncthreads drains vmcnt, so they are complete at the
// coherent point before the done-increment; last block reads pooled with
// agent-scope loads -- R5/R9-validated pattern).
//  k_stats: thread-per-point (R1-proven ~5.1TB/s), 8x float4 loads, unroll 2;
//           f64 partials -> per-block plain stores; block 0 zeroes pooled+done.
//  k_pool : 8 lanes/point; recompute s,rm; 8-lane sums via DPP (0xB1,0x4E,
//           0x141 = 3 VALU adds, zero DS ops). e = exp((c1*s+c2)*rm)
//           (shift-invariant softmax, small scores; absmax 6e-5 R1-R9).
//           z/len cancel under final L2 normalize. Segment-uniform fast path;
//           slow path for ~31 boundary waves. Tail: last block normalizes.

#define TPB 256
#define NBLK 2048

template <int CTRL>
__device__ __forceinline__ float dpp_add(float v) {
  int sh = __builtin_amdgcn_update_dpp(
      0, __builtin_bit_cast(int, v), CTRL, 0xF, 0xF, true);
  return v + __builtin_bit_cast(float, sh);
}
// xor1 = quad_perm[1,0,3,2] = 0xB1 ; xor2 = quad_perm[2,3,0,1] = 0x4E ;
// lane^7 completes the 8-lane sum = ROW_HALF_MIRROR = 0x141

__device__ __forceinline__ float sub8_sum(float v) {
  v = dpp_add<0xB1>(v);
  v = dpp_add<0x4E>(v);
  v = dpp_add<0x141>(v);
  return v;
}

__global__ __launch_bounds__(TPB) void k_stats(
    const float* __restrict__ x, const float* __restrict__ w,
    const float* __restrict__ bptr, double* __restrict__ sumsp,
    float* __restrict__ pooled, int* __restrict__ done, int N) {
  if (blockIdx.x == 0) {            // pooled/done used only by k_pool (launched after)
    for (int i = threadIdx.x; i < 1024; i += TPB) pooled[i] = 0.f;
    if (threadIdx.x == 0) *done = 0;
  }
  int tid = blockIdx.x * blockDim.x + threadIdx.x;
  int stride = gridDim.x * blockDim.x;
  float wreg[32];
#pragma unroll
  for (int j = 0; j < 32; ++j) wreg[j] = w[j];
  const float bv = bptr[0];
  double accS = 0.0, accS2 = 0.0;
#pragma unroll 2
  for (int p = tid; p < N; p += stride) {
    const float4* xp = reinterpret_cast<const float4*>(x) + (size_t)p * 8;
    float dot = 0.f;
#pragma unroll
    for (int q = 0; q < 8; ++q) {
      float4 v = xp[q];
      dot += v.x * wreg[4*q] + v.y * wreg[4*q+1] + v.z * wreg[4*q+2] + v.w * wreg[4*q+3];
    }
    float s = dot + bv;
    accS  += (double)s;
    accS2 += (double)s * (double)s;
  }
#pragma unroll
  for (int off = 32; off > 0; off >>= 1) {
    accS  += __shfl_down(accS, off, 64);
    accS2 += __shfl_down(accS2, off, 64);
  }
  __shared__ double lds[8];
  int wid = threadIdx.x >> 6;
  if ((threadIdx.x & 63) == 0) { lds[wid*2] = accS; lds[wid*2+1] = accS2; }
  __syncthreads();
  if (threadIdx.x == 0) {
    sumsp[blockIdx.x * 2]     = lds[0] + lds[2] + lds[4] + lds[6];
    sumsp[blockIdx.x * 2 + 1] = lds[1] + lds[3] + lds[5] + lds[7];
  }
}

__global__ __launch_bounds__(TPB) void k_pool(
    const float* __restrict__ x, const int* __restrict__ seg,
    const float* __restrict__ w, const float* __restrict__ bptr,
    const double* __restrict__ sumsp, const float* __restrict__ gptr,
    const float* __restrict__ betap, float* __restrict__ pooled,
    int* __restrict__ done, float* __restrict__ out, int N, int chunk) {
  const int tid = threadIdx.x;
  // per-wave reduce of the 2048 stat partials (32KB, L3-hot, deterministic ->
  // identical mu/var in every wave); broadcast from lane 0.
  double a = 0.0, c = 0.0;
  for (int k = tid & 63; k < NBLK; k += 64) {
    a += sumsp[k * 2];
    c += sumsp[k * 2 + 1];
  }
#pragma unroll
  for (int off = 32; off > 0; off >>= 1) {
    a += __shfl_down(a, off, 64);
    c += __shfl_down(c, off, 64);
  }
  a = __shfl(a, 0, 64);
  c = __shfl(c, 0, 64);
  const double mu  = a / (double)N;
  const double var = c / (double)N - mu * mu;
  const float inv = (float)(1.0 / sqrt(var + 1e-5));
  const float c1 = gptr[0] * inv;                 // s_bn = c1*s + c2
  const float c2 = betap[0] - c1 * (float)mu;

  const int lane = tid & 63;
  const int sub  = lane >> 3;      // point slot within the wave's 8-point batch
  const int cg   = lane & 7;       // which float4 of the point
  const float4 w4 = reinterpret_cast<const float4*>(w)[cg];
  const float bv = bptr[0];

  int gid = blockIdx.x * (TPB >> 6) + (tid >> 6);
  int p0 = gid * chunk;                     // chunk is a multiple of 8
  if (p0 < N) {
    int p1 = p0 + chunk; if (p1 > N) p1 = N;
    const float4* x4 = reinterpret_cast<const float4*>(x);
    float4 acc = make_float4(0.f, 0.f, 0.f, 0.f);
    const int segA = seg[p0];
    const int segB = seg[p1 - 1];

    if (segA == segB) {
      // ---- fast path: whole chunk in one segment; DPP-only reductions ----
      int nfull = (p1 - p0) & ~7;
      int pb = p0;
#pragma unroll 8
      for (; pb < p0 + nfull; pb += 8) {
        int p = pb + sub;
        float4 xv = x4[(size_t)p * 8 + cg];
        float d = fmaf(xv.x, w4.x, fmaf(xv.y, w4.y, fmaf(xv.z, w4.z, xv.w * w4.w)));
        float r = (xv.x + xv.y) + (xv.z + xv.w);
        d = sub8_sum(d);
        r = sub8_sum(r);
        float e = __expf(fmaf(c1, d + bv, c2) * (r * 0.03125f));
        acc.x = fmaf(xv.x, e, acc.x);
        acc.y = fmaf(xv.y, e, acc.y);
        acc.z = fmaf(xv.z, e, acc.z);
        acc.w = fmaf(xv.w, e, acc.w);
      }
      if (pb < p1) {                 // tail batch (only the single last active wave)
        int p = pb + sub;
        bool valid = (p < p1);
        int pc = valid ? p : p1 - 1;
        float4 xv = x4[(size_t)pc * 8 + cg];
        float d = fmaf(xv.x, w4.x, fmaf(xv.y, w4.y, fmaf(xv.z, w4.z, xv.w * w4.w)));
        float r = (xv.x + xv.y) + (xv.z + xv.w);
        d = sub8_sum(d);
        r = sub8_sum(r);
        float e = valid ? __expf(fmaf(c1, d + bv, c2) * (r * 0.03125f)) : 0.f;
        acc.x = fmaf(xv.x, e, acc.x);
        acc.y = fmaf(xv.y, e, acc.y);
        acc.z = fmaf(xv.z, e, acc.z);
        acc.w = fmaf(xv.w, e, acc.w);
      }
#pragma unroll
      for (int off = 8; off < 64; off <<= 1) {   // reduce across the 8 point slots
        acc.x += __shfl_xor(acc.x, off);
        acc.y += __shfl_xor(acc.y, off);
        acc.z += __shfl_xor(acc.z, off);
        acc.w += __shfl_xor(acc.w, off);
      }
      if (sub == 0) {
        atomicAdd(&pooled[segA * 32 + cg * 4 + 0], acc.x);
        atomicAdd(&pooled[segA * 32 + cg * 4 + 1], acc.y);
        atomicAdd(&pooled[segA * 32 + cg * 4 + 2], acc.z);
        atomicAdd(&pooled[segA * 32 + cg * 4 + 3], acc.w);
      }
    } else {
      // ---- slow path: chunk crosses a segment boundary (~31 waves total) ----
      int curSeg = segA;
      for (int pb = p0; pb < p1; pb += 8) {
        int p = pb + sub;
        bool valid = (p < p1);
        int pc = valid ? p : p1 - 1;
        int sg = seg[pc];
        float4 xv = x4[(size_t)pc * 8 + cg];
        float d = fmaf(xv.x, w4.x, fmaf(xv.y, w4.y, fmaf(xv.z, w4.z, xv.w * w4.w)));
        float r = (xv.x + xv.y) + (xv.z + xv.w);
        d = sub8_sum(d);
        r = sub8_sum(r);
        float e = valid ? __expf(fmaf(c1, d + bv, c2) * (r * 0.03125f)) : 0.f;
        if (sg != curSeg) {
          atomicAdd(&pooled[curSeg * 32 + cg * 4 + 0], acc.x);
          atomicAdd(&pooled[curSeg * 32 + cg * 4 + 1], acc.y);
          atomicAdd(&pooled[curSeg * 32 + cg * 4 + 2], acc.z);
          atomicAdd(&pooled[curSeg * 32 + cg * 4 + 3], acc.w);
          acc = make_float4(0.f, 0.f, 0.f, 0.f);
          curSeg = sg;
        }
        acc.x = fmaf(xv.x, e, acc.x);
        acc.y = fmaf(xv.y, e, acc.y);
        acc.z = fmaf(xv.z, e, acc.z);
        acc.w = fmaf(xv.w, e, acc.w);
      }
      atomicAdd(&pooled[curSeg * 32 + cg * 4 + 0], acc.x);
      atomicAdd(&pooled[curSeg * 32 + cg * 4 + 1], acc.y);
      atomicAdd(&pooled[curSeg * 32 + cg * 4 + 2], acc.z);
      atomicAdd(&pooled[curSeg * 32 + cg * 4 + 3], acc.w);
    }
  }

  // ---- fenceless last-block-done finalize (saves the k_final dispatch) ----
  // __syncthreads drains vmcnt: this block's pooled atomicAdds (device-scope)
  // have executed at the coherent point before we increment done. No fence.
  __syncthreads();
  __shared__ int lastFlag;
  if (tid == 0) lastFlag = (atomicAdd(done, 1) == NBLK - 1);
  __syncthreads();
  if (lastFlag) {
    for (int i = tid; i < 1024; i += TPB) {
      // agent-scope loads: pooled was written by atomics from other XCDs
      float v = __hip_atomic_load(&pooled[i], __ATOMIC_RELAXED,
                                  __HIP_MEMORY_SCOPE_AGENT);
      float sq = v * v;
#pragma unroll
      for (int off = 16; off > 0; off >>= 1) sq += __shfl_xor(sq, off, 32);
      float norm = sqrtf(sq);               // 32 consecutive threads = one segment
      out[i] = v / fmaxf(norm, 1e-30f);     // z & len cancel under normalize
    }
  }
}

extern "C" void kernel_launch(void* const* d_in, const int* in_sizes, int n_in,
                              void* d_out, int out_size, void* d_ws, size_t ws_size,
                              hipStream_t stream) {
  const float* x     = (const float*)d_in[0];
  const float* w     = (const float*)d_in[1];
  const float* b     = (const float*)d_in[2];
  const float* gamma = (const float*)d_in[3];
  const float* beta  = (const float*)d_in[4];
  const int* seg     = (const int*)d_in[6];
  int N = in_sizes[6];          // 3,170,000
  float* out = (float*)d_out;

  char* ws = (char*)d_ws;
  double* sumsp  = (double*)ws;                        // NBLK*2 doubles (32 KB)
  float*  pooled = (float*)(ws + (size_t)NBLK * 16);   // 1024 floats
  int*    done   = (int*)(ws + (size_t)NBLK * 16 + 4096);

  const int nWaves = NBLK * (TPB / 64);      // 8192
  int chunk = (N + nWaves - 1) / nWaves;
  chunk = (chunk + 7) & ~7;                  // multiple of 8

  k_stats<<<NBLK, TPB, 0, stream>>>(x, w, b, sumsp, pooled, done, N);
  k_pool <<<NBLK, TPB, 0, stream>>>(x, seg, w, b, sumsp, gamma, beta, pooled,
                                    done, out, N, chunk);
}

// Round 11
// 174.087 us; speedup vs baseline: 1.4347x; 1.0067x over previous
//
#include <hip/hip_runtime.h>
#include <hip/hip_bf16.h>

// R11 = R10 + ONE change: k_pool fast path iterates its chunk BACKWARD
// (tail->head). Pass 1 leaves the tail of every chunk resident in the 256MB
// L3; reading tails first (hits, no evictions) then heads (cold) raises L3
// absorption toward the 256/406 ceiling vs ~50% measured forward (R1).
//  k_stats: thread-per-point (R1-proven), 8x float4 loads, unroll 2; f64
//           partials -> per-block plain stores; block 0 zeroes pooled+done.
//  k_pool : 8 lanes/point; recompute s,rm; 8-lane sums via DPP (0xB1,0x4E,
//           0x141): 3 VALU adds, zero DS ops. e = exp((c1*s+c2)*rm)
//           (shift-invariant softmax, small scores; absmax 6e-5 R1-R10).
//           z/len cancel under final L2 normalize. Segment-uniform fast path
//           (backward); slow path forward for ~31 boundary waves.
//           Fenceless last-block-done finalize (R10-validated, neutral cost).

#define TPB 256
#define NBLK 2048

template <int CTRL>
__device__ __forceinline__ float dpp_add(float v) {
  int sh = __builtin_amdgcn_update_dpp(
      0, __builtin_bit_cast(int, v), CTRL, 0xF, 0xF, true);
  return v + __builtin_bit_cast(float, sh);
}
// xor1 = quad_perm[1,0,3,2] = 0xB1 ; xor2 = quad_perm[2,3,0,1] = 0x4E ;
// lane^7 completes the 8-lane sum = ROW_HALF_MIRROR = 0x141

__device__ __forceinline__ float sub8_sum(float v) {
  v = dpp_add<0xB1>(v);
  v = dpp_add<0x4E>(v);
  v = dpp_add<0x141>(v);
  return v;
}

__global__ __launch_bounds__(TPB) void k_stats(
    const float* __restrict__ x, const float* __restrict__ w,
    const float* __restrict__ bptr, double* __restrict__ sumsp,
    float* __restrict__ pooled, int* __restrict__ done, int N) {
  if (blockIdx.x == 0) {            // pooled/done used only by k_pool (launched after)
    for (int i = threadIdx.x; i < 1024; i += TPB) pooled[i] = 0.f;
    if (threadIdx.x == 0) *done = 0;
  }
  int tid = blockIdx.x * blockDim.x + threadIdx.x;
  int stride = gridDim.x * blockDim.x;
  float wreg[32];
#pragma unroll
  for (int j = 0; j < 32; ++j) wreg[j] = w[j];
  const float bv = bptr[0];
  double accS = 0.0, accS2 = 0.0;
#pragma unroll 2
  for (int p = tid; p < N; p += stride) {
    const float4* xp = reinterpret_cast<const float4*>(x) + (size_t)p * 8;
    float dot = 0.f;
#pragma unroll
    for (int q = 0; q < 8; ++q) {
      float4 v = xp[q];
      dot += v.x * wreg[4*q] + v.y * wreg[4*q+1] + v.z * wreg[4*q+2] + v.w * wreg[4*q+3];
    }
    float s = dot + bv;
    accS  += (double)s;
    accS2 += (double)s * (double)s;
  }
#pragma unroll
  for (int off = 32; off > 0; off >>= 1) {
    accS  += __shfl_down(accS, off, 64);
    accS2 += __shfl_down(accS2, off, 64);
  }
  __shared__ double lds[8];
  int wid = threadIdx.x >> 6;
  if ((threadIdx.x & 63) == 0) { lds[wid*2] = accS; lds[wid*2+1] = accS2; }
  __syncthreads();
  if (threadIdx.x == 0) {
    sumsp[blockIdx.x * 2]     = lds[0] + lds[2] + lds[4] + lds[6];
    sumsp[blockIdx.x * 2 + 1] = lds[1] + lds[3] + lds[5] + lds[7];
  }
}

__global__ __launch_bounds__(TPB) void k_pool(
    const float* __restrict__ x, const int* __restrict__ seg,
    const float* __restrict__ w, const float* __restrict__ bptr,
    const double* __restrict__ sumsp, const float* __restrict__ gptr,
    const float* __restrict__ betap, float* __restrict__ pooled,
    int* __restrict__ done, float* __restrict__ out, int N, int chunk) {
  const int tid = threadIdx.x;
  // per-wave reduce of the 2048 stat partials (32KB, L3-hot, deterministic ->
  // identical mu/var in every wave); broadcast from lane 0.
  double a = 0.0, c = 0.0;
  for (int k = tid & 63; k < NBLK; k += 64) {
    a += sumsp[k * 2];
    c += sumsp[k * 2 + 1];
  }
#pragma unroll
  for (int off = 32; off > 0; off >>= 1) {
    a += __shfl_down(a, off, 64);
    c += __shfl_down(c, off, 64);
  }
  a = __shfl(a, 0, 64);
  c = __shfl(c, 0, 64);
  const double mu  = a / (double)N;
  const double var = c / (double)N - mu * mu;
  const float inv = (float)(1.0 / sqrt(var + 1e-5));
  const float c1 = gptr[0] * inv;                 // s_bn = c1*s + c2
  const float c2 = betap[0] - c1 * (float)mu;

  const int lane = tid & 63;
  const int sub  = lane >> 3;      // point slot within the wave's 8-point batch
  const int cg   = lane & 7;       // which float4 of the point
  const float4 w4 = reinterpret_cast<const float4*>(w)[cg];
  const float bv = bptr[0];

  int gid = blockIdx.x * (TPB >> 6) + (tid >> 6);
  int p0 = gid * chunk;                     // chunk is a multiple of 8
  if (p0 < N) {
    int p1 = p0 + chunk; if (p1 > N) p1 = N;
    const float4* x4 = reinterpret_cast<const float4*>(x);
    float4 acc = make_float4(0.f, 0.f, 0.f, 0.f);
    const int segA = seg[p0];
    const int segB = seg[p1 - 1];

    if (segA == segB) {
      // ---- fast path: whole chunk one segment; iterate BACKWARD for L3 hits ----
      int nfull = (p1 - p0) & ~7;
      if (p0 + nfull < p1) {         // partial tail batch first (highest addrs)
        int p = p0 + nfull + sub;
        bool valid = (p < p1);
        int pc = valid ? p : p1 - 1;
        float4 xv = x4[(size_t)pc * 8 + cg];
        float d = fmaf(xv.x, w4.x, fmaf(xv.y, w4.y, fmaf(xv.z, w4.z, xv.w * w4.w)));
        float r = (xv.x + xv.y) + (xv.z + xv.w);
        d = sub8_sum(d);
        r = sub8_sum(r);
        float e = valid ? __expf(fmaf(c1, d + bv, c2) * (r * 0.03125f)) : 0.f;
        acc.x = fmaf(xv.x, e, acc.x);
        acc.y = fmaf(xv.y, e, acc.y);
        acc.z = fmaf(xv.z, e, acc.z);
        acc.w = fmaf(xv.w, e, acc.w);
      }
#pragma unroll 8
      for (int pb = p0 + nfull - 8; pb >= p0; pb -= 8) {
        int p = pb + sub;
        float4 xv = x4[(size_t)p * 8 + cg];
        float d = fmaf(xv.x, w4.x, fmaf(xv.y, w4.y, fmaf(xv.z, w4.z, xv.w * w4.w)));
        float r = (xv.x + xv.y) + (xv.z + xv.w);
        d = sub8_sum(d);
        r = sub8_sum(r);
        float e = __expf(fmaf(c1, d + bv, c2) * (r * 0.03125f));
        acc.x = fmaf(xv.x, e, acc.x);
        acc.y = fmaf(xv.y, e, acc.y);
        acc.z = fmaf(xv.z, e, acc.z);
        acc.w = fmaf(xv.w, e, acc.w);
      }
#pragma unroll
      for (int off = 8; off < 64; off <<= 1) {   // reduce across the 8 point slots
        acc.x += __shfl_xor(acc.x, off);
        acc.y += __shfl_xor(acc.y, off);
        acc.z += __shfl_xor(acc.z, off);
        acc.w += __shfl_xor(acc.w, off);
      }
      if (sub == 0) {
        atomicAdd(&pooled[segA * 32 + cg * 4 + 0], acc.x);
        atomicAdd(&pooled[segA * 32 + cg * 4 + 1], acc.y);
        atomicAdd(&pooled[segA * 32 + cg * 4 + 2], acc.z);
        atomicAdd(&pooled[segA * 32 + cg * 4 + 3], acc.w);
      }
    } else {
      // ---- slow path: chunk crosses a segment boundary (~31 waves; forward) ----
      int curSeg = segA;
      for (int pb = p0; pb < p1; pb += 8) {
        int p = pb + sub;
        bool valid = (p < p1);
        int pc = valid ? p : p1 - 1;
        int sg = seg[pc];
        float4 xv = x4[(size_t)pc * 8 + cg];
        float d = fmaf(xv.x, w4.x, fmaf(xv.y, w4.y, fmaf(xv.z, w4.z, xv.w * w4.w)));
        float r = (xv.x + xv.y) + (xv.z + xv.w);
        d = sub8_sum(d);
        r = sub8_sum(r);
        float e = valid ? __expf(fmaf(c1, d + bv, c2) * (r * 0.03125f)) : 0.f;
        if (sg != curSeg) {
          atomicAdd(&pooled[curSeg * 32 + cg * 4 + 0], acc.x);
          atomicAdd(&pooled[curSeg * 32 + cg * 4 + 1], acc.y);
          atomicAdd(&pooled[curSeg * 32 + cg * 4 + 2], acc.z);
          atomicAdd(&pooled[curSeg * 32 + cg * 4 + 3], acc.w);
          acc = make_float4(0.f, 0.f, 0.f, 0.f);
          curSeg = sg;
        }
        acc.x = fmaf(xv.x, e, acc.x);
        acc.y = fmaf(xv.y, e, acc.y);
        acc.z = fmaf(xv.z, e, acc.z);
        acc.w = fmaf(xv.w, e, acc.w);
      }
      atomicAdd(&pooled[curSeg * 32 + cg * 4 + 0], acc.x);
      atomicAdd(&pooled[curSeg * 32 + cg * 4 + 1], acc.y);
      atomicAdd(&pooled[curSeg * 32 + cg * 4 + 2], acc.z);
      atomicAdd(&pooled[curSeg * 32 + cg * 4 + 3], acc.w);
    }
  }

  // ---- fenceless last-block-done finalize (R10-validated) ----
  __syncthreads();
  __shared__ int lastFlag;
  if (tid == 0) lastFlag = (atomicAdd(done, 1) == NBLK - 1);
  __syncthreads();
  if (lastFlag) {
    for (int i = tid; i < 1024; i += TPB) {
      float v = __hip_atomic_load(&pooled[i], __ATOMIC_RELAXED,
                                  __HIP_MEMORY_SCOPE_AGENT);
      float sq = v * v;
#pragma unroll
      for (int off = 16; off > 0; off >>= 1) sq += __shfl_xor(sq, off, 32);
      float norm = sqrtf(sq);               // 32 consecutive threads = one segment
      out[i] = v / fmaxf(norm, 1e-30f);     // z & len cancel under normalize
    }
  }
}

extern "C" void kernel_launch(void* const* d_in, const int* in_sizes, int n_in,
                              void* d_out, int out_size, void* d_ws, size_t ws_size,
                              hipStream_t stream) {
  const float* x     = (const float*)d_in[0];
  const float* w     = (const float*)d_in[1];
  const float* b     = (const float*)d_in[2];
  const float* gamma = (const float*)d_in[3];
  const float* beta  = (const float*)d_in[4];
  const int* seg     = (const int*)d_in[6];
  int N = in_sizes[6];          // 3,170,000
  float* out = (float*)d_out;

  char* ws = (char*)d_ws;
  double* sumsp  = (double*)ws;                        // NBLK*2 doubles (32 KB)
  float*  pooled = (float*)(ws + (size_t)NBLK * 16);   // 1024 floats
  int*    done   = (int*)(ws + (size_t)NBLK * 16 + 4096);

  const int nWaves = NBLK * (TPB / 64);      // 8192
  int chunk = (N + nWaves - 1) / nWaves;
  chunk = (chunk + 7) & ~7;                  // multiple of 8

  k_stats<<<NBLK, TPB, 0, stream>>>(x, w, b, sumsp, pooled, done, N);
  k_pool <<<NBLK, TPB, 0, stream>>>(x, seg, w, b, sumsp, gamma, beta, pooled,
                                    done, out, N, chunk);
}